// Round 8
// baseline (132.806 us; speedup 1.0000x reference)
//
#include <hip/hip_runtime.h>

#define KCODES 16384
#define CDIM   32
#define NROWS  8192
#define KSPLIT 8                  // chunks (blockIdx.y)
#define CHUNK  (KCODES/KSPLIT)    // 2048
#define WCODES (CHUNK/4)          // 512 codes per wave
#define NT     (WCODES/16)        // 32 MFMA code-tiles per wave
#define RPB    64                 // rows per block
#define REP    2                  // R8 DIAGNOSTIC: 2x inner repeat -> gemm >41us
                                  // -> visible in top-5 counters. Pass 0 sunk via
                                  // asm (rule #17), pass 1 identical -> absmax 0.
#define MARGIN 4.0f               // >>(f16 mfma err ~0.8 + tag noise ~0.2) in l-units

typedef _Float16 half8 __attribute__((ext_vector_type(8)));
typedef float    floatx4 __attribute__((ext_vector_type(4)));

// workspace layout (float indices)
#define WS_MSE   0
#define WS_PLP   1
#define WS_AVGP  16                      // [16384]
#define WS_ENORM (16 + KCODES)           // [16384] fp32, exact
#define WS_ZNORM (16 + 2*KCODES)         // [8192]  fp32
#define WS_PART  (16 + 2*KCODES + NROWS) // float4[KSPLIT][NROWS]
#define WS_E16   (WS_PART + 4*KSPLIT*NROWS)      // f16[16384][32]
#define WS_Z16   (WS_E16 + KCODES*16)            // f16[8192][32]

// output layout (floats): z_q [0, N*C), loss [N*C], idx [N*C+1, ...)
#define OUT_LOSS (NROWS*CDIM)
#define OUT_IDX  (NROWS*CDIM + 1)

// ---------------------------------------------------------------------------
// prep (R12-exact): blocks [0,64): e-rows (enorm + f16 + zero avg_probs);
// blocks [64,96): z-rows (znorm + f16); block 64 zeroes scalars.
// ---------------------------------------------------------------------------
__global__ __launch_bounds__(256) void prep_kernel(const float* __restrict__ z,
                                                   const float* __restrict__ emb,
                                                   float* __restrict__ ws) {
  const int tid = threadIdx.x;
  if (blockIdx.x < 64) {
    int k = blockIdx.x * 256 + tid;
    const float4* p = (const float4*)(emb + (size_t)k * CDIM);
    _Float16* e16 = (_Float16*)(ws + WS_E16);
    float s = 0.f;
    half8 h[4];
#pragma unroll
    for (int i = 0; i < 8; ++i) {
      float4 v = p[i];
      s += v.x*v.x + v.y*v.y + v.z*v.z + v.w*v.w;
      h[i>>1][(i&1)*4+0] = (_Float16)v.x;
      h[i>>1][(i&1)*4+1] = (_Float16)v.y;
      h[i>>1][(i&1)*4+2] = (_Float16)v.z;
      h[i>>1][(i&1)*4+3] = (_Float16)v.w;
    }
    ws[WS_ENORM + k] = s;
    ws[WS_AVGP + k]  = 0.f;
    half8* dst = (half8*)(e16 + (size_t)k*32);
#pragma unroll
    for (int i = 0; i < 4; ++i) dst[i] = h[i];
  } else {
    int b = blockIdx.x - 64;
    int n = b*256 + tid;
    if (b == 0 && tid < 16) ws[tid] = 0.f;
    _Float16* z16 = (_Float16*)(ws + WS_Z16);
    float s = 0.f;
    half8 h[4];
#pragma unroll
    for (int c = 0; c < CDIM; ++c) {
      float v = z[(size_t)b*8192 + c*256 + tid];
      s = fmaf(v, v, s);
      h[c>>3][c&7] = (_Float16)v;
    }
    ws[WS_ZNORM + n] = s;
    half8* dst = (half8*)(z16 + (size_t)n*32);
#pragma unroll
    for (int i = 0; i < 4; ++i) dst[i] = h[i];
  }
}

// ---------------------------------------------------------------------------
// gemm_pass v8 = v7 + REP=2 DIAGNOSTIC. Evidence chain:
//   R0 AGPR shuttles fix: -9us (real). R3 prefetch: -2.5. R4 MFMA hoist:
//   -0.6. R5 occupancy: 0. R7 traffic halving (RPB 64): -1.5.
//   gemm ~25us vs ~6us VALU model; every computable mechanism exonerated;
//   counters unobserved since R2 (fills occlude top-5). STOP GUESSING.
// This round: inner loop runs twice (REP=2). Pass 0 results kept live via
// asm volatile sinks (no DCE), pass 1 recomputes identical state -> part[]
// bit-identical, absmax 0. Dispatch ~50us > fills -> full counters visible.
// Readout: VALUBusy>=70 ->真 VALU-bound, attack op count; VALUBusy<50 ->
// hidden stall (TA/wait); Occ<50% or FETCH balloon -> regalloc/spill.
// ---------------------------------------------------------------------------
__global__ __launch_bounds__(256, 4) void gemm_pass(const float* __restrict__ ws_ro,
                                                    float* __restrict__ ws) {
  __shared__ float2 wdump[4][RPB];      // [wave][row] top-2 tagged floats

  const int tid  = threadIdx.x;
  const int wv   = tid >> 6;
  const int lane = tid & 63;
  const int nn   = lane & 15;
  const int quad = lane >> 4;
  const int n0   = blockIdx.x * RPB;
  const int kb   = blockIdx.y * CHUNK + wv * WCODES;

  const half8* z16v = (const half8*)(ws_ro + WS_Z16);
  const half8* e16v = (const half8*)(ws_ro + WS_E16);
  const float* enorm = ws_ro + WS_ENORM;
  const float* znorm = ws_ro + WS_ZNORM;
  float4* part = (float4*)(ws + WS_PART);

  half8 a0 = z16v[(size_t)(n0 + nn)*4 + quad];
  half8 a1 = z16v[(size_t)(n0 + 16 + nn)*4 + quad];
  half8 a2 = z16v[(size_t)(n0 + 32 + nn)*4 + quad];
  half8 a3 = z16v[(size_t)(n0 + 48 + nn)*4 + quad];

  float t1l[16], t2l[16];

  const int tagbase = wv*WCODES + nn;   // full within-chunk code of tile 0

  // tile-t bases: pb0[t*64] (half8 units, 1024B/tile), pe0[t*16] (64B/tile)
  const half8* pb0 = e16v + ((size_t)(kb + nn)*4 + quad);
  const float* pe0 = enorm + kb + nn;

#pragma unroll
  for (int rep = 0; rep < REP; ++rep) {
    const half8* pb = pb0;
    const float* pe = pe0;
#pragma unroll
    for (int i = 0; i < 16; ++i) { t1l[i] = -3.0e38f; t2l[i] = -3.0e38f; }

    half8 bc = pb[0];  float ec = pe[0];  // tile t (phase A buffer)
    half8 bn;          float en;          // tile t+1 (phase B buffer)

    for (int t = 0; t < NT; t += 2) {
      // ---- phase A: prefetch t+1, compute tile t over 4 row-groups ----
      bn = pb[64];  en = pe[16];
      {
        float neh = -0.5f * ec;                 // broadcast bias: D = dot - en2/2
        floatx4 cb = {neh, neh, neh, neh};
        floatx4 d0 = __builtin_amdgcn_mfma_f32_16x16x32_f16(a0, bc, cb, 0, 0, 0);
        floatx4 d1 = __builtin_amdgcn_mfma_f32_16x16x32_f16(a1, bc, cb, 0, 0, 0);
        floatx4 d2 = __builtin_amdgcn_mfma_f32_16x16x32_f16(a2, bc, cb, 0, 0, 0);
        floatx4 d3 = __builtin_amdgcn_mfma_f32_16x16x32_f16(a3, bc, cb, 0, 0, 0);
        asm("" : "+v"(d0), "+v"(d1), "+v"(d2), "+v"(d3));  // non-volatile VGPR pin
        const int tg = tagbase + 16*t;          // 12-bit within-chunk code
#pragma unroll
        for (int i = 0; i < 16; ++i) {
          float lp = (i < 4) ? d0[i & 3] : (i < 8) ? d1[i & 3]
                   : (i < 12) ? d2[i & 3] : d3[i & 3];
          float v  = __int_as_float((__float_as_int(lp) & 0xFFFFF000) | tg);
          asm("v_med3_f32 %0, %1, %2, %0" : "+v"(t2l[i]) : "v"(v), "v"(t1l[i]));
          asm("v_max_f32 %0, %1, %0"      : "+v"(t1l[i]) : "v"(v));
        }
      }
      // ---- phase B: prefetch t+2 (overwrites consumed bc), compute t+1 ----
      bc = pb[128];  ec = pe[32];               // last iter: mapped overread, unused
      {
        float neh = -0.5f * en;
        floatx4 cb = {neh, neh, neh, neh};
        floatx4 d0 = __builtin_amdgcn_mfma_f32_16x16x32_f16(a0, bn, cb, 0, 0, 0);
        floatx4 d1 = __builtin_amdgcn_mfma_f32_16x16x32_f16(a1, bn, cb, 0, 0, 0);
        floatx4 d2 = __builtin_amdgcn_mfma_f32_16x16x32_f16(a2, bn, cb, 0, 0, 0);
        floatx4 d3 = __builtin_amdgcn_mfma_f32_16x16x32_f16(a3, bn, cb, 0, 0, 0);
        asm("" : "+v"(d0), "+v"(d1), "+v"(d2), "+v"(d3));
        const int tg = tagbase + 16*t + 16;
#pragma unroll
        for (int i = 0; i < 16; ++i) {
          float lp = (i < 4) ? d0[i & 3] : (i < 8) ? d1[i & 3]
                   : (i < 12) ? d2[i & 3] : d3[i & 3];
          float v  = __int_as_float((__float_as_int(lp) & 0xFFFFF000) | tg);
          asm("v_med3_f32 %0, %1, %2, %0" : "+v"(t2l[i]) : "v"(v), "v"(t1l[i]));
          asm("v_max_f32 %0, %1, %0"      : "+v"(t1l[i]) : "v"(v));
        }
      }
      pb += 128; pe += 32;
    }

    if (rep == 0) {
      // keep pass-0 state live (rule #17: no DCE) then discard; pass 1
      // recomputes identical values -> downstream bit-identical.
#pragma unroll
      for (int i = 0; i < 16; ++i)
        asm volatile("" :: "v"(t1l[i]), "v"(t2l[i]));
    }
  }

  // butterfly top-2 merge across the 16 nn-lanes (same-row exchanges only)
  // row of (i, quad): (i>>2)*16 + quad*4 + (i&3)  in [0, RPB)
#pragma unroll
  for (int i = 0; i < 16; ++i) {
    float v1 = t1l[i], v2 = t2l[i];
#pragma unroll
    for (int m = 1; m < 16; m <<= 1) {
      float o1 = __shfl_xor(v1, m);
      float o2 = __shfl_xor(v2, m);
      float mn = fminf(v1, o1);
      v1 = fmaxf(v1, o1);
      v2 = fmaxf(mn, fmaxf(v2, o2));
    }
    if (nn == 0) wdump[wv][(i>>2)*16 + quad*4 + (i&3)] = make_float2(v1, v2);
  }
  __syncthreads();

  // merge 4 waves per row, unpack tags -> (l, code), apply -0.5*znorm here
  if (tid < RPB) {
    float v1 = -3.0e38f, v2 = -3.0e38f;
#pragma unroll
    for (int w = 0; w < 4; ++w) {
      float2 p = wdump[w][tid];
      float mn = fminf(v1, p.x);
      v1 = fmaxf(v1, p.x);
      v2 = fmaxf(mn, fmaxf(v2, p.y));
    }
    float znh = 0.5f * znorm[n0 + tid];
    int b1 = __float_as_int(v1), b2 = __float_as_int(v2);
    int c1i = blockIdx.y*CHUNK + (b1 & 0xFFF);
    int c2i = blockIdx.y*CHUNK + (b2 & 0xFFF);
    float l1 = 200.f * (__int_as_float(b1 & 0xFFFFF000) - znh);
    float l2 = 200.f * (__int_as_float(b2 & 0xFFFFF000) - znh);
    part[(size_t)blockIdx.y*NROWS + n0 + tid] =
        make_float4(l1, __int_as_float(c1i), l2, __int_as_float(c2i));
  }
}

// ---------------------------------------------------------------------------
// combine (+fused zq) — R12-exact, NO gate/finalize tail. R15 showed the
// fused tail's 256 serialized agent-scope atomic loads cost ~50+ us; the
// dispatch-boundary finalize with plain loads is ~5 us (R1..R12 proven).
// ---------------------------------------------------------------------------
__global__ __launch_bounds__(64) void combine_kernel(const float* __restrict__ z,
                                                     const float* __restrict__ emb,
                                                     float* __restrict__ ws,
                                                     float* __restrict__ out) {
  const float4* part = (const float4*)(ws + WS_PART);
  int n = blockIdx.x*64 + threadIdx.x;

  float l[16]; int c[16];
#pragma unroll
  for (int ch = 0; ch < KSPLIT; ++ch) {
    float4 v = part[(size_t)ch*NROWS + n];
    l[ch*2+0] = v.x; c[ch*2+0] = __float_as_int(v.y);
    l[ch*2+1] = v.z; c[ch*2+1] = __float_as_int(v.w);
  }
  float mm = l[0];
#pragma unroll
  for (int i = 1; i < 16; ++i) mm = fmaxf(mm, l[i]);

  int bb = n >> 8, hw = n & 255;
  float zr[32];
  float zn = 0.f;
#pragma unroll
  for (int cc = 0; cc < CDIM; ++cc) {
    zr[cc] = z[(size_t)bb*8192 + cc*256 + hw];
    zn = fmaf(zr[cc], zr[cc], zn);
  }
  float bd = 3.0e38f; int bc = 0x7fffffff;
#pragma unroll
  for (int i = 0; i < 16; ++i) {
    if (l[i] > mm - MARGIN) {
      int code = c[i];
      const float4* er4 = (const float4*)(emb + (size_t)code*CDIM);
      float dot = 0.f;
#pragma unroll
      for (int q = 0; q < 8; ++q) {
        float4 e4 = er4[q];
        dot = fmaf(zr[q*4+0], e4.x, dot);
        dot = fmaf(zr[q*4+1], e4.y, dot);
        dot = fmaf(zr[q*4+2], e4.z, dot);
        dot = fmaf(zr[q*4+3], e4.w, dot);
      }
      float d = (zn + ws[WS_ENORM + code]) - 2.f*dot;   // exact fp32 distance
      if (d < bd || (d == bd && code < bc)) { bd = d; bc = code; }
    }
  }
  out[OUT_IDX + n] = (float)bc;

  // fused zq: straight-through output + MSE (coalesced per-c stores)
  const float* er = emb + (size_t)bc*CDIM;
  float msel = 0.f;
#pragma unroll
  for (int cc = 0; cc < CDIM; ++cc) {
    float zq = er[cc];
    float df = zq - zr[cc];
    msel = fmaf(df, df, msel);
    out[(size_t)bb*8192 + cc*256 + hw] = zr[cc] + (zq - zr[cc]);
  }
  for (int off = 1; off < 64; off <<= 1) msel += __shfl_xor(msel, off);
  if (threadIdx.x == 0) atomicAdd(&ws[WS_MSE], msel);

  // loss softmax from approx pairs (max term = exp(0)=1 -> NaN-proof)
  float s = 0.f;
#pragma unroll
  for (int i = 0; i < 16; ++i) s += __expf(l[i] - mm);
  float lse = mm + __logf(s);

  float plp = 0.f;
#pragma unroll
  for (int i = 0; i < 16; ++i) {
    float u = l[i] - lse;
    float p = __expf(u);
    plp = fmaf(p, u, plp);
    if (p > 1e-12f) atomicAdd(&ws[WS_AVGP + c[i]], p);
  }
  for (int off = 1; off < 64; off <<= 1) plp += __shfl_xor(plp, off);
  if (threadIdx.x == 0) atomicAdd(&ws[WS_PLP], plp);
}

// ---------------------------------------------------------------------------
// finalize (separate dispatch, plain loads — R12-exact): entropy + loss.
// ---------------------------------------------------------------------------
__global__ __launch_bounds__(256) void finalize_kernel(const float* __restrict__ ws,
                                                       float* __restrict__ out) {
  __shared__ float red[256];
  float h = 0.f;
  for (int k = threadIdx.x; k < KCODES; k += 256) {
    float ap = ws[WS_AVGP + k] * (1.f/8192.f);
    h += ap * __logf(ap + 1e-5f);
  }
  red[threadIdx.x] = h;
  __syncthreads();
  for (int st = 128; st > 0; st >>= 1) {
    if (threadIdx.x < st) red[threadIdx.x] += red[threadIdx.x + st];
    __syncthreads();
  }
  if (threadIdx.x == 0) {
    float mse        = ws[WS_MSE] * (1.f/(8192.f*32.f));
    float sample_ent = -ws[WS_PLP] * (1.f/8192.f);
    out[OUT_LOSS] = 1.25f*mse + 0.1f*(sample_ent + red[0]);
  }
}

extern "C" void kernel_launch(void* const* d_in, const int* in_sizes, int n_in,
                              void* d_out, int out_size, void* d_ws, size_t ws_size,
                              hipStream_t stream) {
  (void)in_sizes; (void)n_in; (void)out_size; (void)ws_size;
  const float* z   = (const float*)d_in[0];
  const float* emb = (const float*)d_in[1];
  float* out = (float*)d_out;
  float* ws  = (float*)d_ws;

  prep_kernel    <<<96, 256, 0, stream>>>(z, emb, ws);
  gemm_pass      <<<dim3(NROWS/RPB, KSPLIT), 256, 0, stream>>>(ws, ws);
  combine_kernel <<<NROWS/64, 64, 0, stream>>>(z, emb, ws, out);
  finalize_kernel<<<1, 256, 0, stream>>>(ws, out);
}

// Round 9
// 116.870 us; speedup vs baseline: 1.1364x; 1.1364x over previous
//
#include <hip/hip_runtime.h>

#define KCODES 16384
#define CDIM   32
#define NROWS  8192
#define KSPLIT 8                  // chunks (blockIdx.y)
#define CHUNK  (KCODES/KSPLIT)    // 2048
#define WCODES (CHUNK/4)          // 512 codes per wave
#define NT     (WCODES/16)        // 32 MFMA code-tiles per wave
#define RPB    64                 // rows per block
#define MARGIN 4.0f               // >>(f16 mfma err ~0.8 + tag noise ~0.2) in l-units

typedef _Float16 half8 __attribute__((ext_vector_type(8)));
typedef float    floatx4 __attribute__((ext_vector_type(4)));

// workspace layout (float indices)
#define WS_MSE   0
#define WS_PLP   1
#define WS_AVGP  16                      // [16384]
#define WS_ENORM (16 + KCODES)           // [16384] fp32, exact
#define WS_ZNORM (16 + 2*KCODES)         // [8192]  fp32
#define WS_PART  (16 + 2*KCODES + NROWS) // float4[KSPLIT][NROWS]
#define WS_E16   (WS_PART + 4*KSPLIT*NROWS)      // f16[16384][32]
#define WS_Z16   (WS_E16 + KCODES*16)            // f16[8192][32]

// output layout (floats): z_q [0, N*C), loss [N*C], idx [N*C+1, ...)
#define OUT_LOSS (NROWS*CDIM)
#define OUT_IDX  (NROWS*CDIM + 1)

// ---------------------------------------------------------------------------
// prep (R12-exact): blocks [0,64): e-rows (enorm + f16 + zero avg_probs);
// blocks [64,96): z-rows (znorm + f16); block 64 zeroes scalars.
// ---------------------------------------------------------------------------
__global__ __launch_bounds__(256) void prep_kernel(const float* __restrict__ z,
                                                   const float* __restrict__ emb,
                                                   float* __restrict__ ws) {
  const int tid = threadIdx.x;
  if (blockIdx.x < 64) {
    int k = blockIdx.x * 256 + tid;
    const float4* p = (const float4*)(emb + (size_t)k * CDIM);
    _Float16* e16 = (_Float16*)(ws + WS_E16);
    float s = 0.f;
    half8 h[4];
#pragma unroll
    for (int i = 0; i < 8; ++i) {
      float4 v = p[i];
      s += v.x*v.x + v.y*v.y + v.z*v.z + v.w*v.w;
      h[i>>1][(i&1)*4+0] = (_Float16)v.x;
      h[i>>1][(i&1)*4+1] = (_Float16)v.y;
      h[i>>1][(i&1)*4+2] = (_Float16)v.z;
      h[i>>1][(i&1)*4+3] = (_Float16)v.w;
    }
    ws[WS_ENORM + k] = s;
    ws[WS_AVGP + k]  = 0.f;
    half8* dst = (half8*)(e16 + (size_t)k*32);
#pragma unroll
    for (int i = 0; i < 4; ++i) dst[i] = h[i];
  } else {
    int b = blockIdx.x - 64;
    int n = b*256 + tid;
    if (b == 0 && tid < 16) ws[tid] = 0.f;
    _Float16* z16 = (_Float16*)(ws + WS_Z16);
    float s = 0.f;
    half8 h[4];
#pragma unroll
    for (int c = 0; c < CDIM; ++c) {
      float v = z[(size_t)b*8192 + c*256 + tid];
      s = fmaf(v, v, s);
      h[c>>3][c&7] = (_Float16)v;
    }
    ws[WS_ZNORM + n] = s;
    half8* dst = (half8*)(z16 + (size_t)n*32);
#pragma unroll
    for (int i = 0; i < 4; ++i) dst[i] = h[i];
  }
}

// ---------------------------------------------------------------------------
// gemm_pass v9: SWAPPED-OPERAND screen. R8 REP=2 diagnostic (full counters):
//   VGPR=52 (<< ~98 live), VALUBusy 64% (=15us issue/pass vs 6us model),
//   MfmaUtil 13.7%. => allocator keeps the 32-reg loop-carried t1l/t2l in
//   AGPRs regardless of launch_bounds; every "+v" med3/max pays accvgpr
//   read/write shuttles (~2.5x VALU inflation). Fix is structural:
//   mfma(codeFrag, zFrag) -> D[code=quad*4+j][zrow=nn]: each lane screens
//   4 codes x 1 row per row-group -> loop-carried state 32 -> 8 regs.
//   Fragments may live in AGPRs for free (MFMA reads AGPRs natively).
// Bit-exactness: same products, same C bias value (-.5*enorm[code], now a
//   per-lane float4), same K accumulate order -> D bitwise identical; tags
//   (wv*512)|(16t)|(quad*4+j) are the same integers; top-2 of the same
//   distinct multiset (tags in low bits) is order-independent; quad-
//   butterfly (xor 16,32) replaces nn-butterfly -> part[] bit-identical.
// ---------------------------------------------------------------------------
__global__ __launch_bounds__(256, 4) void gemm_pass(const float* __restrict__ ws_ro,
                                                    float* __restrict__ ws) {
  __shared__ float2 wdump[4][RPB];      // [wave][row] top-2 tagged floats

  const int tid  = threadIdx.x;
  const int wv   = tid >> 6;
  const int lane = tid & 63;
  const int nn   = lane & 15;
  const int quad = lane >> 4;
  const int n0   = blockIdx.x * RPB;
  const int kb   = blockIdx.y * CHUNK + wv * WCODES;

  const half8* z16v = (const half8*)(ws_ro + WS_Z16);
  const half8* e16v = (const half8*)(ws_ro + WS_E16);
  const float* enorm = ws_ro + WS_ENORM;
  const float* znorm = ws_ro + WS_ZNORM;
  float4* part = (float4*)(ws + WS_PART);

  // z-row B-fragments (lane nn <-> z-row of each 16-row group)
  half8 zb0 = z16v[(size_t)(n0 + nn)*4 + quad];
  half8 zb1 = z16v[(size_t)(n0 + 16 + nn)*4 + quad];
  half8 zb2 = z16v[(size_t)(n0 + 32 + nn)*4 + quad];
  half8 zb3 = z16v[(size_t)(n0 + 48 + nn)*4 + quad];

  // per-lane top-2 state: 4 row-groups, row (g*16+nn), codes {quad*4+j}
  float t1[4], t2[4];
#pragma unroll
  for (int g = 0; g < 4; ++g) { t1[g] = -3.0e38f; t2[g] = -3.0e38f; }

  // tag bases: code = wv*512 | 16t | quad*4+j  (disjoint bit fields)
  const int tgq = wv*WCODES + quad*4;
  const int tgq0 = tgq, tgq1 = tgq|1, tgq2 = tgq|2, tgq3 = tgq|3;

  // code A-fragment pointer (lane nn <-> code row of tile): 64 half8/tile
  const half8* pb = e16v + ((size_t)(kb + nn)*4 + quad);
  // enorm per-lane float4: 4 float4/tile, quad picks one
  const float4* pq = (const float4*)(enorm + kb) + quad;

  half8 bc = pb[0];  float4 e4c = pq[0];   // tile t
  half8 bn;          float4 e4n;           // tile t+1

  for (int t = 0; t < NT; t += 2) {
    // ---- phase A: prefetch t+1, compute tile t ----
    bn = pb[64];  e4n = pq[4];
    {
      floatx4 cb = {-0.5f*e4c.x, -0.5f*e4c.y, -0.5f*e4c.z, -0.5f*e4c.w};
      floatx4 d0 = __builtin_amdgcn_mfma_f32_16x16x32_f16(bc, zb0, cb, 0, 0, 0);
      floatx4 d1 = __builtin_amdgcn_mfma_f32_16x16x32_f16(bc, zb1, cb, 0, 0, 0);
      floatx4 d2 = __builtin_amdgcn_mfma_f32_16x16x32_f16(bc, zb2, cb, 0, 0, 0);
      floatx4 d3 = __builtin_amdgcn_mfma_f32_16x16x32_f16(bc, zb3, cb, 0, 0, 0);
      asm("" : "+v"(d0), "+v"(d1), "+v"(d2), "+v"(d3));   // arch-VGPR pin
      const int s16t = 16*t;                              // uniform (SGPR)
      const int vt0 = tgq0 | s16t, vt1 = tgq1 | s16t,
                vt2 = tgq2 | s16t, vt3 = tgq3 | s16t;
#pragma unroll
      for (int g = 0; g < 4; ++g) {
        floatx4 d = (g == 0) ? d0 : (g == 1) ? d1 : (g == 2) ? d2 : d3;
        float v0 = __int_as_float((__float_as_int(d[0]) & 0xFFFFF000) | vt0);
        float v1 = __int_as_float((__float_as_int(d[1]) & 0xFFFFF000) | vt1);
        float v2 = __int_as_float((__float_as_int(d[2]) & 0xFFFFF000) | vt2);
        float v3 = __int_as_float((__float_as_int(d[3]) & 0xFFFFF000) | vt3);
        asm("v_med3_f32 %0, %1, %2, %0" : "+v"(t2[g]) : "v"(v0), "v"(t1[g]));
        asm("v_max_f32 %0, %1, %0"      : "+v"(t1[g]) : "v"(v0));
        asm("v_med3_f32 %0, %1, %2, %0" : "+v"(t2[g]) : "v"(v1), "v"(t1[g]));
        asm("v_max_f32 %0, %1, %0"      : "+v"(t1[g]) : "v"(v1));
        asm("v_med3_f32 %0, %1, %2, %0" : "+v"(t2[g]) : "v"(v2), "v"(t1[g]));
        asm("v_max_f32 %0, %1, %0"      : "+v"(t1[g]) : "v"(v2));
        asm("v_med3_f32 %0, %1, %2, %0" : "+v"(t2[g]) : "v"(v3), "v"(t1[g]));
        asm("v_max_f32 %0, %1, %0"      : "+v"(t1[g]) : "v"(v3));
      }
    }
    // ---- phase B: prefetch t+2 (overwrites consumed bc), compute t+1 ----
    bc = pb[128];  e4c = pq[8];               // last iter: mapped overread, unused
    {
      floatx4 cb = {-0.5f*e4n.x, -0.5f*e4n.y, -0.5f*e4n.z, -0.5f*e4n.w};
      floatx4 d0 = __builtin_amdgcn_mfma_f32_16x16x32_f16(bn, zb0, cb, 0, 0, 0);
      floatx4 d1 = __builtin_amdgcn_mfma_f32_16x16x32_f16(bn, zb1, cb, 0, 0, 0);
      floatx4 d2 = __builtin_amdgcn_mfma_f32_16x16x32_f16(bn, zb2, cb, 0, 0, 0);
      floatx4 d3 = __builtin_amdgcn_mfma_f32_16x16x32_f16(bn, zb3, cb, 0, 0, 0);
      asm("" : "+v"(d0), "+v"(d1), "+v"(d2), "+v"(d3));
      const int s16t = 16*t + 16;
      const int vt0 = tgq0 | s16t, vt1 = tgq1 | s16t,
                vt2 = tgq2 | s16t, vt3 = tgq3 | s16t;
#pragma unroll
      for (int g = 0; g < 4; ++g) {
        floatx4 d = (g == 0) ? d0 : (g == 1) ? d1 : (g == 2) ? d2 : d3;
        float v0 = __int_as_float((__float_as_int(d[0]) & 0xFFFFF000) | vt0);
        float v1 = __int_as_float((__float_as_int(d[1]) & 0xFFFFF000) | vt1);
        float v2 = __int_as_float((__float_as_int(d[2]) & 0xFFFFF000) | vt2);
        float v3 = __int_as_float((__float_as_int(d[3]) & 0xFFFFF000) | vt3);
        asm("v_med3_f32 %0, %1, %2, %0" : "+v"(t2[g]) : "v"(v0), "v"(t1[g]));
        asm("v_max_f32 %0, %1, %0"      : "+v"(t1[g]) : "v"(v0));
        asm("v_med3_f32 %0, %1, %2, %0" : "+v"(t2[g]) : "v"(v1), "v"(t1[g]));
        asm("v_max_f32 %0, %1, %0"      : "+v"(t1[g]) : "v"(v1));
        asm("v_med3_f32 %0, %1, %2, %0" : "+v"(t2[g]) : "v"(v2), "v"(t1[g]));
        asm("v_max_f32 %0, %1, %0"      : "+v"(t1[g]) : "v"(v2));
        asm("v_med3_f32 %0, %1, %2, %0" : "+v"(t2[g]) : "v"(v3), "v"(t1[g]));
        asm("v_max_f32 %0, %1, %0"      : "+v"(t1[g]) : "v"(v3));
      }
    }
    pb += 128; pq += 8;
  }

  // quad-butterfly top-2 merge (lanes xor 16, 32 share the same row nn)
#pragma unroll
  for (int g = 0; g < 4; ++g) {
    float v1 = t1[g], v2 = t2[g];
#pragma unroll
    for (int m = 16; m < 64; m <<= 1) {
      float o1 = __shfl_xor(v1, m);
      float o2 = __shfl_xor(v2, m);
      float mn = fminf(v1, o1);
      v1 = fmaxf(v1, o1);
      v2 = fmaxf(mn, fmaxf(v2, o2));
    }
    if (quad == 0) wdump[wv][g*16 + nn] = make_float2(v1, v2);
  }
  __syncthreads();

  // merge 4 waves per row, unpack tags -> (l, code), apply -0.5*znorm here
  if (tid < RPB) {
    float v1 = -3.0e38f, v2 = -3.0e38f;
#pragma unroll
    for (int w = 0; w < 4; ++w) {
      float2 p = wdump[w][tid];
      float mn = fminf(v1, p.x);
      v1 = fmaxf(v1, p.x);
      v2 = fmaxf(mn, fmaxf(v2, p.y));
    }
    float znh = 0.5f * znorm[n0 + tid];
    int b1 = __float_as_int(v1), b2 = __float_as_int(v2);
    int c1i = blockIdx.y*CHUNK + (b1 & 0xFFF);
    int c2i = blockIdx.y*CHUNK + (b2 & 0xFFF);
    float l1 = 200.f * (__int_as_float(b1 & 0xFFFFF000) - znh);
    float l2 = 200.f * (__int_as_float(b2 & 0xFFFFF000) - znh);
    part[(size_t)blockIdx.y*NROWS + n0 + tid] =
        make_float4(l1, __int_as_float(c1i), l2, __int_as_float(c2i));
  }
}

// ---------------------------------------------------------------------------
// combine (+fused zq) — R12-exact, NO gate/finalize tail. R15 showed the
// fused tail's 256 serialized agent-scope atomic loads cost ~50+ us; the
// dispatch-boundary finalize with plain loads is ~5 us (R1..R12 proven).
// ---------------------------------------------------------------------------
__global__ __launch_bounds__(64) void combine_kernel(const float* __restrict__ z,
                                                     const float* __restrict__ emb,
                                                     float* __restrict__ ws,
                                                     float* __restrict__ out) {
  const float4* part = (const float4*)(ws + WS_PART);
  int n = blockIdx.x*64 + threadIdx.x;

  float l[16]; int c[16];
#pragma unroll
  for (int ch = 0; ch < KSPLIT; ++ch) {
    float4 v = part[(size_t)ch*NROWS + n];
    l[ch*2+0] = v.x; c[ch*2+0] = __float_as_int(v.y);
    l[ch*2+1] = v.z; c[ch*2+1] = __float_as_int(v.w);
  }
  float mm = l[0];
#pragma unroll
  for (int i = 1; i < 16; ++i) mm = fmaxf(mm, l[i]);

  int bb = n >> 8, hw = n & 255;
  float zr[32];
  float zn = 0.f;
#pragma unroll
  for (int cc = 0; cc < CDIM; ++cc) {
    zr[cc] = z[(size_t)bb*8192 + cc*256 + hw];
    zn = fmaf(zr[cc], zr[cc], zn);
  }
  float bd = 3.0e38f; int bc = 0x7fffffff;
#pragma unroll
  for (int i = 0; i < 16; ++i) {
    if (l[i] > mm - MARGIN) {
      int code = c[i];
      const float4* er4 = (const float4*)(emb + (size_t)code*CDIM);
      float dot = 0.f;
#pragma unroll
      for (int q = 0; q < 8; ++q) {
        float4 e4 = er4[q];
        dot = fmaf(zr[q*4+0], e4.x, dot);
        dot = fmaf(zr[q*4+1], e4.y, dot);
        dot = fmaf(zr[q*4+2], e4.z, dot);
        dot = fmaf(zr[q*4+3], e4.w, dot);
      }
      float d = (zn + ws[WS_ENORM + code]) - 2.f*dot;   // exact fp32 distance
      if (d < bd || (d == bd && code < bc)) { bd = d; bc = code; }
    }
  }
  out[OUT_IDX + n] = (float)bc;

  // fused zq: straight-through output + MSE (coalesced per-c stores)
  const float* er = emb + (size_t)bc*CDIM;
  float msel = 0.f;
#pragma unroll
  for (int cc = 0; cc < CDIM; ++cc) {
    float zq = er[cc];
    float df = zq - zr[cc];
    msel = fmaf(df, df, msel);
    out[(size_t)bb*8192 + cc*256 + hw] = zr[cc] + (zq - zr[cc]);
  }
  for (int off = 1; off < 64; off <<= 1) msel += __shfl_xor(msel, off);
  if (threadIdx.x == 0) atomicAdd(&ws[WS_MSE], msel);

  // loss softmax from approx pairs (max term = exp(0)=1 -> NaN-proof)
  float s = 0.f;
#pragma unroll
  for (int i = 0; i < 16; ++i) s += __expf(l[i] - mm);
  float lse = mm + __logf(s);

  float plp = 0.f;
#pragma unroll
  for (int i = 0; i < 16; ++i) {
    float u = l[i] - lse;
    float p = __expf(u);
    plp = fmaf(p, u, plp);
    if (p > 1e-12f) atomicAdd(&ws[WS_AVGP + c[i]], p);
  }
  for (int off = 1; off < 64; off <<= 1) plp += __shfl_xor(plp, off);
  if (threadIdx.x == 0) atomicAdd(&ws[WS_PLP], plp);
}

// ---------------------------------------------------------------------------
// finalize (separate dispatch, plain loads — R12-exact): entropy + loss.
// ---------------------------------------------------------------------------
__global__ __launch_bounds__(256) void finalize_kernel(const float* __restrict__ ws,
                                                       float* __restrict__ out) {
  __shared__ float red[256];
  float h = 0.f;
  for (int k = threadIdx.x; k < KCODES; k += 256) {
    float ap = ws[WS_AVGP + k] * (1.f/8192.f);
    h += ap * __logf(ap + 1e-5f);
  }
  red[threadIdx.x] = h;
  __syncthreads();
  for (int st = 128; st > 0; st >>= 1) {
    if (threadIdx.x < st) red[threadIdx.x] += red[threadIdx.x + st];
    __syncthreads();
  }
  if (threadIdx.x == 0) {
    float mse        = ws[WS_MSE] * (1.f/(8192.f*32.f));
    float sample_ent = -ws[WS_PLP] * (1.f/8192.f);
    out[OUT_LOSS] = 1.25f*mse + 0.1f*(sample_ent + red[0]);
  }
}

extern "C" void kernel_launch(void* const* d_in, const int* in_sizes, int n_in,
                              void* d_out, int out_size, void* d_ws, size_t ws_size,
                              hipStream_t stream) {
  (void)in_sizes; (void)n_in; (void)out_size; (void)ws_size;
  const float* z   = (const float*)d_in[0];
  const float* emb = (const float*)d_in[1];
  float* out = (float*)d_out;
  float* ws  = (float*)d_ws;

  prep_kernel    <<<96, 256, 0, stream>>>(z, emb, ws);
  gemm_pass      <<<dim3(NROWS/RPB, KSPLIT), 256, 0, stream>>>(ws, ws);
  combine_kernel <<<NROWS/64, 64, 0, stream>>>(z, emb, ws, out);
  finalize_kernel<<<1, 256, 0, stream>>>(ws, out);
}

// Round 10
// 114.177 us; speedup vs baseline: 1.1632x; 1.0236x over previous
//
#include <hip/hip_runtime.h>

#define KCODES 16384
#define CDIM   32
#define NROWS  8192
#define KSPLIT 8                  // chunks (blockIdx.y)
#define CHUNK  (KCODES/KSPLIT)    // 2048
#define WCODES (CHUNK/4)          // 512 codes per wave
#define NT     (WCODES/16)        // 32 MFMA code-tiles per wave
#define RPB    64                 // rows per block
#define MARGIN 4.0f               // >>(f16 mfma err ~0.8 + tag noise ~0.2) in l-units

typedef _Float16 half8 __attribute__((ext_vector_type(8)));
typedef float    floatx4 __attribute__((ext_vector_type(4)));

// workspace layout (float indices)
#define WS_MSE   0
#define WS_PLP   1
#define WS_AVGP  16                      // [16384]
#define WS_ENORM (16 + KCODES)           // [16384] fp32, exact
#define WS_ZNORM (16 + 2*KCODES)         // [8192]  fp32
#define WS_PART  (16 + 2*KCODES + NROWS) // float4[KSPLIT][NROWS]
#define WS_E16   (WS_PART + 4*KSPLIT*NROWS)      // f16[16384][32]
#define WS_Z16   (WS_E16 + KCODES*16)            // f16[8192][32]
#define WS_ENH   (WS_Z16 + NROWS*16)     // [16384] fp32 = -0.5*enorm (R10)

// output layout (floats): z_q [0, N*C), loss [N*C], idx [N*C+1, ...)
#define OUT_LOSS (NROWS*CDIM)
#define OUT_IDX  (NROWS*CDIM + 1)

// ---------------------------------------------------------------------------
// prep: blocks [0,64): e-rows (enorm + ENH + f16 + zero avg_probs);
// blocks [64,96): z-rows (znorm + f16); block 64 zeroes scalars.
// R10: also stores ENH[k] = -0.5f*enorm[k] (exact fp32 scaling) so gemm's
// MFMA bias is a pure load instead of 8 v_mul per body.
// ---------------------------------------------------------------------------
__global__ __launch_bounds__(256) void prep_kernel(const float* __restrict__ z,
                                                   const float* __restrict__ emb,
                                                   float* __restrict__ ws) {
  const int tid = threadIdx.x;
  if (blockIdx.x < 64) {
    int k = blockIdx.x * 256 + tid;
    const float4* p = (const float4*)(emb + (size_t)k * CDIM);
    _Float16* e16 = (_Float16*)(ws + WS_E16);
    float s = 0.f;
    half8 h[4];
#pragma unroll
    for (int i = 0; i < 8; ++i) {
      float4 v = p[i];
      s += v.x*v.x + v.y*v.y + v.z*v.z + v.w*v.w;
      h[i>>1][(i&1)*4+0] = (_Float16)v.x;
      h[i>>1][(i&1)*4+1] = (_Float16)v.y;
      h[i>>1][(i&1)*4+2] = (_Float16)v.z;
      h[i>>1][(i&1)*4+3] = (_Float16)v.w;
    }
    ws[WS_ENORM + k] = s;
    ws[WS_ENH + k]   = -0.5f * s;       // exact: sign+exponent ops only
    ws[WS_AVGP + k]  = 0.f;
    half8* dst = (half8*)(e16 + (size_t)k*32);
#pragma unroll
    for (int i = 0; i < 4; ++i) dst[i] = h[i];
  } else {
    int b = blockIdx.x - 64;
    int n = b*256 + tid;
    if (b == 0 && tid < 16) ws[tid] = 0.f;
    _Float16* z16 = (_Float16*)(ws + WS_Z16);
    float s = 0.f;
    half8 h[4];
#pragma unroll
    for (int c = 0; c < CDIM; ++c) {
      float v = z[(size_t)b*8192 + c*256 + tid];
      s = fmaf(v, v, s);
      h[c>>3][c&7] = (_Float16)v;
    }
    ws[WS_ZNORM + n] = s;
    half8* dst = (half8*)(z16 + (size_t)n*32);
#pragma unroll
    for (int i = 0; i < 4; ++i) dst[i] = h[i];
  }
}

// ---------------------------------------------------------------------------
// gemm_pass v10: GUARANTEED-3-OP screen. Evidence chain:
//   R8 REP=2: marginal compute pass = 16us @ VALUBusy 64%; source model =
//   ~6.5us (3.2 ops/elem). R9 state-size cut: flat => shuttles were gone
//   since R2 ("v" asm constraints bind arch VGPRs). Residual 2x bloat can
//   only be compiler discretion in the element path: unfused and/or (VOP3
//   can't take the 0xFFFFF000 literal -> needs SGPR mask) + 8 cb muls.
// Changes vs v9 (values bit-identical):
//   - element op = ONE asm block: v_and_or_b32 (mask via "s") -> v_med3_f32
//     (reads old t1) -> v_max_f32. Exactly 3 VALU, no discretion.
//   - cb = direct load of prep-computed ENH (= -0.5*enorm, exact).
// DECISION RULE (stated pre-bench): total >= 115 => stream already lean,
// structure at floor; declare ROOFLINE next round (fills 82us dominate).
// ---------------------------------------------------------------------------
__global__ __launch_bounds__(256, 4) void gemm_pass(const float* __restrict__ ws_ro,
                                                    float* __restrict__ ws) {
  __shared__ float2 wdump[4][RPB];      // [wave][row] top-2 tagged floats

  const int tid  = threadIdx.x;
  const int wv   = tid >> 6;
  const int lane = tid & 63;
  const int nn   = lane & 15;
  const int quad = lane >> 4;
  const int n0   = blockIdx.x * RPB;
  const int kb   = blockIdx.y * CHUNK + wv * WCODES;

  const half8* z16v = (const half8*)(ws_ro + WS_Z16);
  const half8* e16v = (const half8*)(ws_ro + WS_E16);
  const float* enh   = ws_ro + WS_ENH;
  const float* znorm = ws_ro + WS_ZNORM;
  float4* part = (float4*)(ws + WS_PART);

  // z-row B-fragments (lane nn <-> z-row of each 16-row group)
  half8 zb0 = z16v[(size_t)(n0 + nn)*4 + quad];
  half8 zb1 = z16v[(size_t)(n0 + 16 + nn)*4 + quad];
  half8 zb2 = z16v[(size_t)(n0 + 32 + nn)*4 + quad];
  half8 zb3 = z16v[(size_t)(n0 + 48 + nn)*4 + quad];

  // per-lane top-2 state: 4 row-groups, row (g*16+nn), codes {quad*4+j}
  float t1[4], t2[4];
#pragma unroll
  for (int g = 0; g < 4; ++g) { t1[g] = -3.0e38f; t2[g] = -3.0e38f; }

  // tag bases: code = wv*512 | 16t | quad*4+j  (disjoint bit fields)
  const int tgq = wv*WCODES + quad*4;
  const int tgq0 = tgq, tgq1 = tgq|1, tgq2 = tgq|2, tgq3 = tgq|3;
  const unsigned maskhi = 0xFFFFF000u;  // hoisted to SGPR by "s" constraint

  // code A-fragment pointer (lane nn <-> code row of tile): 64 half8/tile
  const half8* pb = e16v + ((size_t)(kb + nn)*4 + quad);
  // ENH per-lane float4 (pre-negated-halved enorm): 4 float4/tile
  const float4* pq = (const float4*)(enh + kb) + quad;

#define SCREEN1(dv, vt, g)                                                  \
  { float _tmp;                                                             \
    asm("v_and_or_b32 %2, %3, %4, %5\n\t"                                   \
        "v_med3_f32 %1, %2, %0, %1\n\t"                                     \
        "v_max_f32 %0, %2, %0"                                              \
        : "+v"(t1[g]), "+v"(t2[g]), "=&v"(_tmp)                             \
        : "v"(dv), "s"(maskhi), "v"(vt)); }

  half8 bc = pb[0];  float4 e4c = pq[0];   // tile t
  half8 bn;          float4 e4n;           // tile t+1

  for (int t = 0; t < NT; t += 2) {
    // ---- phase A: prefetch t+1, compute tile t ----
    bn = pb[64];  e4n = pq[4];
    {
      floatx4 cb = {e4c.x, e4c.y, e4c.z, e4c.w};   // bias pre-negated in prep
      floatx4 d0 = __builtin_amdgcn_mfma_f32_16x16x32_f16(bc, zb0, cb, 0, 0, 0);
      floatx4 d1 = __builtin_amdgcn_mfma_f32_16x16x32_f16(bc, zb1, cb, 0, 0, 0);
      floatx4 d2 = __builtin_amdgcn_mfma_f32_16x16x32_f16(bc, zb2, cb, 0, 0, 0);
      floatx4 d3 = __builtin_amdgcn_mfma_f32_16x16x32_f16(bc, zb3, cb, 0, 0, 0);
      asm("" : "+v"(d0), "+v"(d1), "+v"(d2), "+v"(d3));   // arch-VGPR pin
      const int s16t = 16*t;
      const int vt0 = tgq0 | s16t, vt1 = tgq1 | s16t,
                vt2 = tgq2 | s16t, vt3 = tgq3 | s16t;
#pragma unroll
      for (int g = 0; g < 4; ++g) {
        floatx4 d = (g == 0) ? d0 : (g == 1) ? d1 : (g == 2) ? d2 : d3;
        SCREEN1(d[0], vt0, g)
        SCREEN1(d[1], vt1, g)
        SCREEN1(d[2], vt2, g)
        SCREEN1(d[3], vt3, g)
      }
    }
    // ---- phase B: prefetch t+2 (overwrites consumed bc), compute t+1 ----
    bc = pb[128];  e4c = pq[8];               // last iter: mapped overread, unused
    {
      floatx4 cb = {e4n.x, e4n.y, e4n.z, e4n.w};
      floatx4 d0 = __builtin_amdgcn_mfma_f32_16x16x32_f16(bn, zb0, cb, 0, 0, 0);
      floatx4 d1 = __builtin_amdgcn_mfma_f32_16x16x32_f16(bn, zb1, cb, 0, 0, 0);
      floatx4 d2 = __builtin_amdgcn_mfma_f32_16x16x32_f16(bn, zb2, cb, 0, 0, 0);
      floatx4 d3 = __builtin_amdgcn_mfma_f32_16x16x32_f16(bn, zb3, cb, 0, 0, 0);
      asm("" : "+v"(d0), "+v"(d1), "+v"(d2), "+v"(d3));
      const int s16t = 16*t + 16;
      const int vt0 = tgq0 | s16t, vt1 = tgq1 | s16t,
                vt2 = tgq2 | s16t, vt3 = tgq3 | s16t;
#pragma unroll
      for (int g = 0; g < 4; ++g) {
        floatx4 d = (g == 0) ? d0 : (g == 1) ? d1 : (g == 2) ? d2 : d3;
        SCREEN1(d[0], vt0, g)
        SCREEN1(d[1], vt1, g)
        SCREEN1(d[2], vt2, g)
        SCREEN1(d[3], vt3, g)
      }
    }
    pb += 128; pq += 8;
  }
#undef SCREEN1

  // quad-butterfly top-2 merge (lanes xor 16, 32 share the same row nn)
#pragma unroll
  for (int g = 0; g < 4; ++g) {
    float v1 = t1[g], v2 = t2[g];
#pragma unroll
    for (int m = 16; m < 64; m <<= 1) {
      float o1 = __shfl_xor(v1, m);
      float o2 = __shfl_xor(v2, m);
      float mn = fminf(v1, o1);
      v1 = fmaxf(v1, o1);
      v2 = fmaxf(mn, fmaxf(v2, o2));
    }
    if (quad == 0) wdump[wv][g*16 + nn] = make_float2(v1, v2);
  }
  __syncthreads();

  // merge 4 waves per row, unpack tags -> (l, code), apply -0.5*znorm here
  if (tid < RPB) {
    float v1 = -3.0e38f, v2 = -3.0e38f;
#pragma unroll
    for (int w = 0; w < 4; ++w) {
      float2 p = wdump[w][tid];
      float mn = fminf(v1, p.x);
      v1 = fmaxf(v1, p.x);
      v2 = fmaxf(mn, fmaxf(v2, p.y));
    }
    float znh = 0.5f * znorm[n0 + tid];
    int b1 = __float_as_int(v1), b2 = __float_as_int(v2);
    int c1i = blockIdx.y*CHUNK + (b1 & 0xFFF);
    int c2i = blockIdx.y*CHUNK + (b2 & 0xFFF);
    float l1 = 200.f * (__int_as_float(b1 & 0xFFFFF000) - znh);
    float l2 = 200.f * (__int_as_float(b2 & 0xFFFFF000) - znh);
    part[(size_t)blockIdx.y*NROWS + n0 + tid] =
        make_float4(l1, __int_as_float(c1i), l2, __int_as_float(c2i));
  }
}

// ---------------------------------------------------------------------------
// combine (+fused zq) — R12-exact, NO gate/finalize tail. R15 showed the
// fused tail's 256 serialized agent-scope atomic loads cost ~50+ us; the
// dispatch-boundary finalize with plain loads is ~5 us (R1..R12 proven).
// ---------------------------------------------------------------------------
__global__ __launch_bounds__(64) void combine_kernel(const float* __restrict__ z,
                                                     const float* __restrict__ emb,
                                                     float* __restrict__ ws,
                                                     float* __restrict__ out) {
  const float4* part = (const float4*)(ws + WS_PART);
  int n = blockIdx.x*64 + threadIdx.x;

  float l[16]; int c[16];
#pragma unroll
  for (int ch = 0; ch < KSPLIT; ++ch) {
    float4 v = part[(size_t)ch*NROWS + n];
    l[ch*2+0] = v.x; c[ch*2+0] = __float_as_int(v.y);
    l[ch*2+1] = v.z; c[ch*2+1] = __float_as_int(v.w);
  }
  float mm = l[0];
#pragma unroll
  for (int i = 1; i < 16; ++i) mm = fmaxf(mm, l[i]);

  int bb = n >> 8, hw = n & 255;
  float zr[32];
  float zn = 0.f;
#pragma unroll
  for (int cc = 0; cc < CDIM; ++cc) {
    zr[cc] = z[(size_t)bb*8192 + cc*256 + hw];
    zn = fmaf(zr[cc], zr[cc], zn);
  }
  float bd = 3.0e38f; int bc = 0x7fffffff;
#pragma unroll
  for (int i = 0; i < 16; ++i) {
    if (l[i] > mm - MARGIN) {
      int code = c[i];
      const float4* er4 = (const float4*)(emb + (size_t)code*CDIM);
      float dot = 0.f;
#pragma unroll
      for (int q = 0; q < 8; ++q) {
        float4 e4 = er4[q];
        dot = fmaf(zr[q*4+0], e4.x, dot);
        dot = fmaf(zr[q*4+1], e4.y, dot);
        dot = fmaf(zr[q*4+2], e4.z, dot);
        dot = fmaf(zr[q*4+3], e4.w, dot);
      }
      float d = (zn + ws[WS_ENORM + code]) - 2.f*dot;   // exact fp32 distance
      if (d < bd || (d == bd && code < bc)) { bd = d; bc = code; }
    }
  }
  out[OUT_IDX + n] = (float)bc;

  // fused zq: straight-through output + MSE (coalesced per-c stores)
  const float* er = emb + (size_t)bc*CDIM;
  float msel = 0.f;
#pragma unroll
  for (int cc = 0; cc < CDIM; ++cc) {
    float zq = er[cc];
    float df = zq - zr[cc];
    msel = fmaf(df, df, msel);
    out[(size_t)bb*8192 + cc*256 + hw] = zr[cc] + (zq - zr[cc]);
  }
  for (int off = 1; off < 64; off <<= 1) msel += __shfl_xor(msel, off);
  if (threadIdx.x == 0) atomicAdd(&ws[WS_MSE], msel);

  // loss softmax from approx pairs (max term = exp(0)=1 -> NaN-proof)
  float s = 0.f;
#pragma unroll
  for (int i = 0; i < 16; ++i) s += __expf(l[i] - mm);
  float lse = mm + __logf(s);

  float plp = 0.f;
#pragma unroll
  for (int i = 0; i < 16; ++i) {
    float u = l[i] - lse;
    float p = __expf(u);
    plp = fmaf(p, u, plp);
    if (p > 1e-12f) atomicAdd(&ws[WS_AVGP + c[i]], p);
  }
  for (int off = 1; off < 64; off <<= 1) plp += __shfl_xor(plp, off);
  if (threadIdx.x == 0) atomicAdd(&ws[WS_PLP], plp);
}

// ---------------------------------------------------------------------------
// finalize (separate dispatch, plain loads — R12-exact): entropy + loss.
// ---------------------------------------------------------------------------
__global__ __launch_bounds__(256) void finalize_kernel(const float* __restrict__ ws,
                                                       float* __restrict__ out) {
  __shared__ float red[256];
  float h = 0.f;
  for (int k = threadIdx.x; k < KCODES; k += 256) {
    float ap = ws[WS_AVGP + k] * (1.f/8192.f);
    h += ap * __logf(ap + 1e-5f);
  }
  red[threadIdx.x] = h;
  __syncthreads();
  for (int st = 128; st > 0; st >>= 1) {
    if (threadIdx.x < st) red[threadIdx.x] += red[threadIdx.x + st];
    __syncthreads();
  }
  if (threadIdx.x == 0) {
    float mse        = ws[WS_MSE] * (1.f/(8192.f*32.f));
    float sample_ent = -ws[WS_PLP] * (1.f/8192.f);
    out[OUT_LOSS] = 1.25f*mse + 0.1f*(sample_ent + red[0]);
  }
}

extern "C" void kernel_launch(void* const* d_in, const int* in_sizes, int n_in,
                              void* d_out, int out_size, void* d_ws, size_t ws_size,
                              hipStream_t stream) {
  (void)in_sizes; (void)n_in; (void)out_size; (void)ws_size;
  const float* z   = (const float*)d_in[0];
  const float* emb = (const float*)d_in[1];
  float* out = (float*)d_out;
  float* ws  = (float*)d_ws;

  prep_kernel    <<<96, 256, 0, stream>>>(z, emb, ws);
  gemm_pass      <<<dim3(NROWS/RPB, KSPLIT), 256, 0, stream>>>(ws, ws);
  combine_kernel <<<NROWS/64, 64, 0, stream>>>(z, emb, ws, out);
  finalize_kernel<<<1, 256, 0, stream>>>(ws, out);
}